// Round 3
// baseline (16681.026 us; speedup 1.0000x reference)
//
#include <hip/hip_runtime.h>

// Bidirectional GRU, T=512, B=64, I=512, H=512, fp32 in/out.
// out layout: [T][B][2H] (fwd j in [0,H), bwd j in [H,2H)), then hT_f [B][H], hT_b [B][H].
//
// R3: ONE persistent kernel runs all 512 steps. 32 blocks (16/dir) x 512 thr.
// Inter-block sync: per-direction monotonic barrier in ws (device-scope atomics,
// release fence = buffer_wbl2 flushes XCD L2, acquire fence = buffer_inv).
// Hot loop is pure bf16 loads + mfma: x pre-converted to bf16 in ws, h kept as
// bf16 ping-pong in ws (written in epilogue), weights bf16 in ws.

#define TT 512
#define BB 64
#define II 512
#define HH 512
#define PDIR 16   // blocks per direction

typedef __attribute__((ext_vector_type(8))) short short8;
typedef __attribute__((ext_vector_type(4))) float f32x4;
typedef unsigned short u16;

// ws layout (bytes)
#define WS_BAR_OFF 0
#define WS_W_OFF   1024
#define WS_W_BYTES ((size_t)2 * 3 * HH * 1024 * 2)       // 6291456
#define WS_X_OFF   ((size_t)7340032)                     // 7 MB, 4K aligned
#define WS_X_BYTES ((size_t)TT * BB * II * 2)            // 33554432
#define WS_H_OFF   ((size_t)40894464)                    // 4K aligned
#define WS_H_BYTES ((size_t)2 * 2 * BB * HH * 2)         // 262144
#define WS_NEED_A  (WS_H_OFF + WS_H_BYTES)
#define WS_NEED_B  ((size_t)(WS_W_OFF) + WS_W_BYTES + 1024)

static __device__ __forceinline__ short f2bf(float f) {
    union { float f; unsigned int u; } v; v.f = f;
    unsigned int r = (v.u + 0x7fffu + ((v.u >> 16) & 1u)) >> 16;  // RNE
    return (short)r;
}

static __device__ __forceinline__ short8 ldcvt(const float* __restrict__ p) {
    const float4 a = *(const float4*)p;
    const float4 b = *(const float4*)(p + 4);
    short8 r;
    r[0] = f2bf(a.x); r[1] = f2bf(a.y); r[2] = f2bf(a.z); r[3] = f2bf(a.w);
    r[4] = f2bf(b.x); r[5] = f2bf(b.y); r[6] = f2bf(b.z); r[7] = f2bf(b.w);
    return r;
}

static __device__ __forceinline__ short8 ldbf(const u16* __restrict__ p) {
    return *(const short8*)p;  // 16 B
}

// ---- staging kernels -------------------------------------------------------

// weights -> bf16 [dir][gate][j][k 0..1023] (k<512: Wih, k>=512: Whh)
__global__ __launch_bounds__(256) void convert_w_kernel(
    const float* __restrict__ Wih_f, const float* __restrict__ Whh_f,
    const float* __restrict__ Wih_b, const float* __restrict__ Whh_b,
    u16* __restrict__ wsW)
{
    const int total4 = 2 * 3 * HH * 1024 / 4;
    for (int i = blockIdx.x * 256 + threadIdx.x; i < total4; i += gridDim.x * 256) {
        const int e   = i * 4;
        const int k   = e & 1023;
        const int row = e >> 10;
        const int dir = row / 1536;
        const int rem = row - dir * 1536;
        const int g   = rem >> 9;
        const int j   = rem & 511;
        const float* W = (k < 512) ? (dir ? Wih_b : Wih_f) : (dir ? Whh_b : Whh_f);
        const int kk = k & 511;
        const float4 v = *(const float4*)&W[(size_t)(g * HH + j) * II + kk];
        u16 o[4] = { (u16)f2bf(v.x), (u16)f2bf(v.y), (u16)f2bf(v.z), (u16)f2bf(v.w) };
        *(ushort4*)&wsW[e] = *(ushort4*)o;
    }
}

__global__ __launch_bounds__(256) void convert_x_kernel(
    const float* __restrict__ inp, u16* __restrict__ xbf)
{
    const int total4 = TT * BB * II / 4;
    for (int i = blockIdx.x * 256 + threadIdx.x; i < total4; i += gridDim.x * 256) {
        const float4 v = ((const float4*)inp)[i];
        u16 o[4] = { (u16)f2bf(v.x), (u16)f2bf(v.y), (u16)f2bf(v.z), (u16)f2bf(v.w) };
        ((ushort4*)xbf)[i] = *(ushort4*)o;
    }
}

// h0 -> bf16 into hbuf slot 1 of each dir (step 0 reads slot (0+1)&1 = 1)
__global__ __launch_bounds__(256) void convert_h0_kernel(
    const float* __restrict__ h0f, const float* __restrict__ h0b,
    u16* __restrict__ hbuf)
{
    const int per = BB * HH / 4;          // 8192 float4 per dir
    for (int i = blockIdx.x * 256 + threadIdx.x; i < 2 * per; i += gridDim.x * 256) {
        const int dir = (i >= per);
        const int l   = dir ? (i - per) : i;
        const float4 v = ((const float4*)(dir ? h0b : h0f))[l];
        u16 o[4] = { (u16)f2bf(v.x), (u16)f2bf(v.y), (u16)f2bf(v.z), (u16)f2bf(v.w) };
        ((ushort4*)(hbuf + (size_t)(dir * 2 + 1) * BB * HH))[l] = *(ushort4*)o;
    }
}

// ---- persistent GRU --------------------------------------------------------

template <bool XBF>
__global__ __launch_bounds__(512) void gru_persistent(
    const float* __restrict__ inp,
    const float* __restrict__ h0f, const float* __restrict__ h0b,
    const float* __restrict__ bih_f, const float* __restrict__ bhh_f,
    const float* __restrict__ bih_b, const float* __restrict__ bhh_b,
    const u16* __restrict__ wsW, const u16* __restrict__ xbf,
    u16* __restrict__ hbuf, int* __restrict__ bar,
    float* __restrict__ out)
{
    const int bk   = blockIdx.x;
    const int dir  = bk >> 4;          // 0 fwd, 1 bwd
    const int sub  = bk & 15;
    const int tid  = threadIdx.x;
    const int wave = tid >> 6;
    const int lane = tid & 63;
    const int mt   = wave & 3;                 // batch tile 0..3
    const int jt   = sub * 2 + (wave >> 2);    // j tile 0..31
    const int nm   = lane & 15;
    const int kq   = lane >> 4;
    const int koff = kq * 8;
    const int jg   = jt * 16 + nm;
    const int arow = mt * 16 + nm;

    const float* bih = dir ? bih_b : bih_f;
    const float* bhh = dir ? bhh_b : bhh_f;
    const float* h0  = dir ? h0b  : h0f;

    const float b_r  = bih[jg] + bhh[jg];
    const float b_z  = bih[HH + jg] + bhh[HH + jg];
    const float b_in = bih[2 * HH + jg];
    const float b_hn = bhh[2 * HH + jg];

    const size_t wbase = ((size_t)(dir * 3) * HH + jg) * 1024;
    const u16* wb0 = wsW + wbase;
    const u16* wb1 = wb0 + (size_t)HH * 1024;
    const u16* wb2 = wb1 + (size_t)HH * 1024;

    u16* hb_d = hbuf + (size_t)dir * 2 * BB * HH;
    int* cnt  = bar + dir * 64;   // separate cacheline per direction

    for (int s = 0; s < TT; ++s) {
        const int t  = dir ? (TT - 1 - s) : s;
        const int tp = dir ? (t + 1) : (t - 1);

        const u16*   xb   = XBF ? (xbf + ((size_t)t * BB + arow) * II) : nullptr;
        const float* xr   = inp + ((size_t)t * BB + arow) * II;
        const u16*   hbr  = hb_d + (size_t)((s + 1) & 1) * BB * HH + (size_t)arow * HH;
        const float* hr32 = (s == 0) ? (h0 + (size_t)arow * HH)
                                     : (out + ((size_t)tp * BB + arow) * (2 * HH) + dir * HH);

        f32x4 ar = {0.f, 0.f, 0.f, 0.f};
        f32x4 az = ar, ain = ar, ahn = ar;

        #pragma unroll 4
        for (int k0 = 0; k0 < II; k0 += 32) {
            const int kk = k0 + koff;
            const short8 a = XBF ? ldbf(xb + kk) : ldcvt(xr + kk);
            ar  = __builtin_amdgcn_mfma_f32_16x16x32_bf16(a, ldbf(wb0 + kk), ar, 0, 0, 0);
            az  = __builtin_amdgcn_mfma_f32_16x16x32_bf16(a, ldbf(wb1 + kk), az, 0, 0, 0);
            ain = __builtin_amdgcn_mfma_f32_16x16x32_bf16(a, ldbf(wb2 + kk), ain, 0, 0, 0);
        }
        #pragma unroll 4
        for (int k0 = 0; k0 < HH; k0 += 32) {
            const int kk = k0 + koff;
            const short8 a = XBF ? ldbf(hbr + kk) : ldcvt(hr32 + kk);
            ar  = __builtin_amdgcn_mfma_f32_16x16x32_bf16(a, ldbf(wb0 + 512 + kk), ar, 0, 0, 0);
            az  = __builtin_amdgcn_mfma_f32_16x16x32_bf16(a, ldbf(wb1 + 512 + kk), az, 0, 0, 0);
            ahn = __builtin_amdgcn_mfma_f32_16x16x32_bf16(a, ldbf(wb2 + 512 + kk), ahn, 0, 0, 0);
        }

        // epilogue: C/D layout col=lane&15 (j), row=(lane>>4)*4+reg (batch)
        u16* hbw = hb_d + (size_t)(s & 1) * BB * HH;
        #pragma unroll
        for (int rg = 0; rg < 4; ++rg) {
            const int be = mt * 16 + kq * 4 + rg;
            const float hprev = (s == 0)
                ? h0[(size_t)be * HH + jg]
                : out[((size_t)tp * BB + be) * (2 * HH) + dir * HH + jg];
            const float r = 1.f / (1.f + __expf(-(ar[rg] + b_r)));
            const float z = 1.f / (1.f + __expf(-(az[rg] + b_z)));
            const float n = tanhf(ain[rg] + b_in + r * (ahn[rg] + b_hn));
            const float hnew = (1.f - z) * n + z * hprev;
            out[((size_t)t * BB + be) * (2 * HH) + dir * HH + jg] = hnew;
            if (XBF) hbw[(size_t)be * HH + jg] = (u16)f2bf(hnew);
            if (s == TT - 1) {
                out[(size_t)TT * BB * 2 * HH + (size_t)dir * BB * HH + (size_t)be * HH + jg] = hnew;
            }
        }

        if (s == TT - 1) break;   // no barrier needed after last step

        // inter-block barrier (per direction, monotonic count)
        __syncthreads();   // all waves' stores issued & vmcnt-drained per-wave
        if (tid == 0) {
            __builtin_amdgcn_fence(__ATOMIC_RELEASE, "agent");      // wb L2
            __hip_atomic_fetch_add(cnt, 1, __ATOMIC_RELAXED, __HIP_MEMORY_SCOPE_AGENT);
            const int target = PDIR * (s + 1);
            while (__hip_atomic_load(cnt, __ATOMIC_RELAXED, __HIP_MEMORY_SCOPE_AGENT) < target)
                __builtin_amdgcn_s_sleep(1);
            __builtin_amdgcn_fence(__ATOMIC_ACQUIRE, "agent");      // inv L1/L2
        }
        __syncthreads();
    }
}

// ---- R2-style fallback (tiny ws) ------------------------------------------

__global__ __launch_bounds__(64) void gru_step_kernel_nows(
    const float* __restrict__ inp,
    const float* __restrict__ h0f, const float* __restrict__ h0b,
    const float* __restrict__ Wih_f, const float* __restrict__ Whh_f,
    const float* __restrict__ bih_f, const float* __restrict__ bhh_f,
    const float* __restrict__ Wih_b, const float* __restrict__ Whh_b,
    const float* __restrict__ bih_b, const float* __restrict__ bhh_b,
    float* __restrict__ out, int s)
{
    const int jt = blockIdx.x, mt = blockIdx.y, dir = blockIdx.z;
    const int lane = threadIdx.x;
    const int nm = lane & 15, kq = lane >> 4, j0 = jt * 16, koff = kq * 8;
    const int t  = dir ? (TT - 1 - s) : s;
    const int tp = dir ? (t + 1) : (t - 1);
    const float* Wih = dir ? Wih_b : Wih_f;
    const float* Whh = dir ? Whh_b : Whh_f;
    const float* bih = dir ? bih_b : bih_f;
    const float* bhh = dir ? bhh_b : bhh_f;
    const float* h0  = dir ? h0b : h0f;
    const int arow = mt * 16 + nm;
    const float* xrow = inp + ((size_t)t * BB + arow) * II;
    const float* hrow = (s == 0) ? (h0 + (size_t)arow * HH)
                                 : (out + ((size_t)tp * BB + arow) * 2 * HH + dir * HH);
    const float* wi0 = Wih + (size_t)(0 * HH + j0 + nm) * II;
    const float* wi1 = Wih + (size_t)(1 * HH + j0 + nm) * II;
    const float* wi2 = Wih + (size_t)(2 * HH + j0 + nm) * II;
    const float* wh0 = Whh + (size_t)(0 * HH + j0 + nm) * II;
    const float* wh1 = Whh + (size_t)(1 * HH + j0 + nm) * II;
    const float* wh2 = Whh + (size_t)(2 * HH + j0 + nm) * II;
    f32x4 ar = {0.f, 0.f, 0.f, 0.f};
    f32x4 az = ar, ain = ar, ahn = ar;
    #pragma unroll 4
    for (int k0 = 0; k0 < II; k0 += 32) {
        const int kk = k0 + koff;
        const short8 a = ldcvt(xrow + kk);
        ar  = __builtin_amdgcn_mfma_f32_16x16x32_bf16(a, ldcvt(wi0 + kk), ar, 0, 0, 0);
        az  = __builtin_amdgcn_mfma_f32_16x16x32_bf16(a, ldcvt(wi1 + kk), az, 0, 0, 0);
        ain = __builtin_amdgcn_mfma_f32_16x16x32_bf16(a, ldcvt(wi2 + kk), ain, 0, 0, 0);
    }
    #pragma unroll 4
    for (int k0 = 0; k0 < HH; k0 += 32) {
        const int kk = k0 + koff;
        const short8 a = ldcvt(hrow + kk);
        ar  = __builtin_amdgcn_mfma_f32_16x16x32_bf16(a, ldcvt(wh0 + kk), ar, 0, 0, 0);
        az  = __builtin_amdgcn_mfma_f32_16x16x32_bf16(a, ldcvt(wh1 + kk), az, 0, 0, 0);
        ahn = __builtin_amdgcn_mfma_f32_16x16x32_bf16(a, ldcvt(wh2 + kk), ahn, 0, 0, 0);
    }
    const int jg = j0 + nm;
    const float b_r  = bih[jg] + bhh[jg];
    const float b_z  = bih[HH + jg] + bhh[HH + jg];
    const float b_in = bih[2 * HH + jg];
    const float b_hn = bhh[2 * HH + jg];
    #pragma unroll
    for (int rg = 0; rg < 4; ++rg) {
        const int be = mt * 16 + kq * 4 + rg;
        const float hprev = (s == 0)
            ? h0[(size_t)be * HH + jg]
            : out[((size_t)tp * BB + be) * 2 * HH + dir * HH + jg];
        const float r = 1.f / (1.f + __expf(-(ar[rg] + b_r)));
        const float z = 1.f / (1.f + __expf(-(az[rg] + b_z)));
        const float n = tanhf(ain[rg] + b_in + r * (ahn[rg] + b_hn));
        const float hnew = (1.f - z) * n + z * hprev;
        out[((size_t)t * BB + be) * 2 * HH + dir * HH + jg] = hnew;
        if (s == TT - 1)
            out[(size_t)TT * BB * 2 * HH + (size_t)dir * BB * HH + (size_t)be * HH + jg] = hnew;
    }
}

// ---- launch ----------------------------------------------------------------

extern "C" void kernel_launch(void* const* d_in, const int* in_sizes, int n_in,
                              void* d_out, int out_size, void* d_ws, size_t ws_size,
                              hipStream_t stream) {
    (void)in_sizes; (void)n_in; (void)out_size;

    const float* inp   = (const float*)d_in[0];
    const float* h0f   = (const float*)d_in[1];
    const float* h0b   = (const float*)d_in[2];
    const float* Wih_f = (const float*)d_in[3];
    const float* Whh_f = (const float*)d_in[4];
    const float* bih_f = (const float*)d_in[5];
    const float* bhh_f = (const float*)d_in[6];
    const float* Wih_b = (const float*)d_in[7];
    const float* Whh_b = (const float*)d_in[8];
    const float* bih_b = (const float*)d_in[9];
    const float* bhh_b = (const float*)d_in[10];
    float* out = (float*)d_out;

    char* ws = (char*)d_ws;
    int*  bar  = (int*)(ws + WS_BAR_OFF);
    u16*  wsW  = (u16*)(ws + WS_W_OFF);
    u16*  xbf  = (u16*)(ws + WS_X_OFF);
    u16*  hbuf = (u16*)(ws + WS_H_OFF);

    if (ws_size >= WS_NEED_A) {
        hipMemsetAsync(ws + WS_BAR_OFF, 0, 1024, stream);
        convert_w_kernel<<<1024, 256, 0, stream>>>(Wih_f, Whh_f, Wih_b, Whh_b, wsW);
        convert_x_kernel<<<2048, 256, 0, stream>>>(inp, xbf);
        convert_h0_kernel<<<64, 256, 0, stream>>>(h0f, h0b, hbuf);
        gru_persistent<true><<<32, 512, 0, stream>>>(
            inp, h0f, h0b, bih_f, bhh_f, bih_b, bhh_b,
            wsW, xbf, hbuf, bar, out);
    } else if (ws_size >= WS_NEED_B) {
        hipMemsetAsync(ws + WS_BAR_OFF, 0, 1024, stream);
        convert_w_kernel<<<1024, 256, 0, stream>>>(Wih_f, Whh_f, Wih_b, Whh_b, wsW);
        gru_persistent<false><<<32, 512, 0, stream>>>(
            inp, h0f, h0b, bih_f, bhh_f, bih_b, bhh_b,
            wsW, nullptr, nullptr, bar, out);
    } else {
        const dim3 grid(HH / 16, BB / 16, 2);
        for (int s = 0; s < TT; ++s) {
            gru_step_kernel_nows<<<grid, dim3(64), 0, stream>>>(
                inp, h0f, h0b, Wih_f, Whh_f, bih_f, bhh_f,
                Wih_b, Whh_b, bih_b, bhh_b, out, s);
        }
    }
}

// Round 4
// 12488.039 us; speedup vs baseline: 1.3358x; 1.3358x over previous
//
#include <hip/hip_runtime.h>

// Bidirectional GRU, T=512, B=64, I=512, H=512, fp32 in/out.
// out layout: [T][B][2H] (fwd j in [0,H), bwd j in [H,2H)), then hT_f, hT_b [B][H].
//
// R4: persistent kernel, 32 blocks (16/dir) x 512 thr. Cross-block h handoff via
// DEVICE-SCOPE RELAXED ATOMICS (sc0 sc1 -> memory-side L3, coherent) on a 256 KB
// bf16 ping-pong buffer -- NO agent fences, so weights/x stay hot in L1/L2.
// fp32 hprev for the z-blend is carried in registers (same lane produces the same
// (b,j) cell every step). Barrier: per-dir monotonic counter, relaxed atomics.

#define TT 512
#define BB 64
#define II 512
#define HH 512
#define PDIR 16   // blocks per direction

typedef __attribute__((ext_vector_type(8))) short short8;
typedef __attribute__((ext_vector_type(4))) float f32x4;
typedef unsigned short u16;
typedef unsigned long long u64;

// ws layout (bytes)
#define WS_BAR_OFF  0
#define WS_W_OFF    ((size_t)4096)
#define WS_W_BYTES  ((size_t)2 * 3 * HH * 1024 * 2)   // 6291456
#define WS_X_OFF    ((size_t)6295552)                 // 4K aligned
#define WS_X_BYTES  ((size_t)TT * BB * II * 2)        // 33554432
#define WS_HB_OFF   ((size_t)39849984)                // 4K aligned
#define WS_HB_BYTES ((size_t)2 * 2 * BB * HH * 2)     // 262144
#define WS_NEED_A   (WS_HB_OFF + WS_HB_BYTES)         // ~40.1 MB

static __device__ __forceinline__ short f2bf(float f) {
    union { float f; unsigned int u; } v; v.f = f;
    unsigned int r = (v.u + 0x7fffu + ((v.u >> 16) & 1u)) >> 16;  // RNE
    return (short)r;
}

static __device__ __forceinline__ short8 ldcvt(const float* __restrict__ p) {
    const float4 a = *(const float4*)p;
    const float4 b = *(const float4*)(p + 4);
    short8 r;
    r[0] = f2bf(a.x); r[1] = f2bf(a.y); r[2] = f2bf(a.z); r[3] = f2bf(a.w);
    r[4] = f2bf(b.x); r[5] = f2bf(b.y); r[6] = f2bf(b.z); r[7] = f2bf(b.w);
    return r;
}

static __device__ __forceinline__ short8 ldbf(const u16* __restrict__ p) {
    return *(const short8*)p;  // 16 B cached load
}

// coherent (device-scope, L1/L2-bypass) 16 B bf16 fragment load
static __device__ __forceinline__ short8 ld8_coh(const u16* p) {
    union { u64 u[2]; short8 s; } v;
    v.u[0] = __hip_atomic_load((const u64*)p,       __ATOMIC_RELAXED, __HIP_MEMORY_SCOPE_AGENT);
    v.u[1] = __hip_atomic_load((const u64*)(p + 4), __ATOMIC_RELAXED, __HIP_MEMORY_SCOPE_AGENT);
    return v.s;
}

static __device__ __forceinline__ void st16_coh(u16* p, u16 v) {
    __hip_atomic_store(p, v, __ATOMIC_RELAXED, __HIP_MEMORY_SCOPE_AGENT);
}

// ---- staging kernels -------------------------------------------------------

// weights -> bf16 [dir][gate][j][k 0..1023] (k<512: Wih, k>=512: Whh)
__global__ __launch_bounds__(256) void convert_w_kernel(
    const float* __restrict__ Wih_f, const float* __restrict__ Whh_f,
    const float* __restrict__ Wih_b, const float* __restrict__ Whh_b,
    u16* __restrict__ wsW)
{
    const int total4 = 2 * 3 * HH * 1024 / 4;
    for (int i = blockIdx.x * 256 + threadIdx.x; i < total4; i += gridDim.x * 256) {
        const int e   = i * 4;
        const int k   = e & 1023;
        const int row = e >> 10;
        const int dir = row / 1536;
        const int rem = row - dir * 1536;
        const int g   = rem >> 9;
        const int j   = rem & 511;
        const float* W = (k < 512) ? (dir ? Wih_b : Wih_f) : (dir ? Whh_b : Whh_f);
        const int kk = k & 511;
        const float4 v = *(const float4*)&W[(size_t)(g * HH + j) * II + kk];
        u16 o[4] = { (u16)f2bf(v.x), (u16)f2bf(v.y), (u16)f2bf(v.z), (u16)f2bf(v.w) };
        *(ushort4*)&wsW[e] = *(ushort4*)o;
    }
}

__global__ __launch_bounds__(256) void convert_x_kernel(
    const float* __restrict__ inp, u16* __restrict__ xbf)
{
    const int total4 = TT * BB * II / 4;
    for (int i = blockIdx.x * 256 + threadIdx.x; i < total4; i += gridDim.x * 256) {
        const float4 v = ((const float4*)inp)[i];
        u16 o[4] = { (u16)f2bf(v.x), (u16)f2bf(v.y), (u16)f2bf(v.z), (u16)f2bf(v.w) };
        ((ushort4*)xbf)[i] = *(ushort4*)o;
    }
}

// h0 -> bf16 into ping-pong slot 0 of each dir (step 0 reads slot 0)
__global__ __launch_bounds__(256) void convert_h0_kernel(
    const float* __restrict__ h0f, const float* __restrict__ h0b,
    u16* __restrict__ hbuf)
{
    const int per = BB * HH / 4;
    for (int i = blockIdx.x * 256 + threadIdx.x; i < 2 * per; i += gridDim.x * 256) {
        const int dir = (i >= per);
        const int l   = dir ? (i - per) : i;
        const float4 v = ((const float4*)(dir ? h0b : h0f))[l];
        u16 o[4] = { (u16)f2bf(v.x), (u16)f2bf(v.y), (u16)f2bf(v.z), (u16)f2bf(v.w) };
        ((ushort4*)(hbuf + (size_t)(dir * 2) * BB * HH))[l] = *(ushort4*)o;
    }
}

// ---- persistent GRU --------------------------------------------------------

__global__ __launch_bounds__(512, 2) void gru_persistent(
    const float* __restrict__ h0f, const float* __restrict__ h0b,
    const float* __restrict__ bih_f, const float* __restrict__ bhh_f,
    const float* __restrict__ bih_b, const float* __restrict__ bhh_b,
    const u16* __restrict__ wsW, const u16* __restrict__ xbf,
    u16* hbuf, int* bar, float* __restrict__ out)
{
    const int bk   = blockIdx.x;
    const int dir  = bk >> 4;          // 0 fwd, 1 bwd
    const int sub  = bk & 15;
    const int tid  = threadIdx.x;
    const int wave = tid >> 6;
    const int lane = tid & 63;
    const int mt   = wave & 3;                 // batch tile 0..3
    const int jt   = sub * 2 + (wave >> 2);    // j tile 0..31
    const int nm   = lane & 15;
    const int kq   = lane >> 4;
    const int koff = kq * 8;
    const int jg   = jt * 16 + nm;
    const int arow = mt * 16 + nm;

    const float* bih = dir ? bih_b : bih_f;
    const float* bhh = dir ? bhh_b : bhh_f;
    const float* h0  = dir ? h0b  : h0f;

    const float b_r  = bih[jg] + bhh[jg];
    const float b_z  = bih[HH + jg] + bhh[HH + jg];
    const float b_in = bih[2 * HH + jg];
    const float b_hn = bhh[2 * HH + jg];

    const size_t wbase = ((size_t)(dir * 3) * HH + jg) * 1024;
    const u16* wb0 = wsW + wbase;
    const u16* wb1 = wb0 + (size_t)HH * 1024;
    const u16* wb2 = wb1 + (size_t)HH * 1024;

    u16* hb_d = hbuf + (size_t)dir * 2 * BB * HH;
    int* cnt  = bar + dir * 64;   // separate cacheline per direction

    // fp32 hprev carried in registers: this lane owns cells (mt*16+kq*4+rg, jg)
    // of the C/D tile every step.
    f32x4 hp;
    #pragma unroll
    for (int rg = 0; rg < 4; ++rg)
        hp[rg] = h0[(size_t)(mt * 16 + kq * 4 + rg) * HH + jg];

    for (int s = 0; s < TT; ++s) {
        const int t = dir ? (TT - 1 - s) : s;

        f32x4 ar = {0.f, 0.f, 0.f, 0.f};
        f32x4 az = ar, ain = ar, ahn = ar;

        // ---- x half (independent of h): run BEFORE waiting on the barrier ----
        const u16* xb = xbf + ((size_t)t * BB + arow) * II;
        #pragma unroll 4
        for (int k0 = 0; k0 < II; k0 += 32) {
            const int kk = k0 + koff;
            const short8 a = ldbf(xb + kk);
            ar  = __builtin_amdgcn_mfma_f32_16x16x32_bf16(a, ldbf(wb0 + kk), ar, 0, 0, 0);
            az  = __builtin_amdgcn_mfma_f32_16x16x32_bf16(a, ldbf(wb1 + kk), az, 0, 0, 0);
            ain = __builtin_amdgcn_mfma_f32_16x16x32_bf16(a, ldbf(wb2 + kk), ain, 0, 0, 0);
        }

        // ---- wait for h_{s-1} from all blocks of this direction ----
        if (s > 0) {
            const int target = PDIR * s;
            while (__hip_atomic_load(cnt, __ATOMIC_RELAXED, __HIP_MEMORY_SCOPE_AGENT) < target) {}
            __builtin_amdgcn_fence(__ATOMIC_ACQUIRE, "workgroup");  // compiler ordering; no cache ops
        }

        // ---- h half: prefetch all 16 coherent A-frags, then MFMA ----
        const u16* hbr = hb_d + (size_t)(s & 1) * BB * HH + (size_t)arow * HH;
        short8 ha[16];
        #pragma unroll
        for (int i = 0; i < 16; ++i)
            ha[i] = ld8_coh(hbr + i * 32 + koff);
        #pragma unroll
        for (int i = 0; i < 16; ++i) {
            const int kk = i * 32 + koff;
            ar  = __builtin_amdgcn_mfma_f32_16x16x32_bf16(ha[i], ldbf(wb0 + 512 + kk), ar, 0, 0, 0);
            az  = __builtin_amdgcn_mfma_f32_16x16x32_bf16(ha[i], ldbf(wb1 + 512 + kk), az, 0, 0, 0);
            ahn = __builtin_amdgcn_mfma_f32_16x16x32_bf16(ha[i], ldbf(wb2 + 512 + kk), ahn, 0, 0, 0);
        }

        // ---- epilogue: C/D layout col=lane&15 (j), row=(lane>>4)*4+reg (batch) ----
        u16* hbw = hb_d + (size_t)((s + 1) & 1) * BB * HH;
        #pragma unroll
        for (int rg = 0; rg < 4; ++rg) {
            const int be = mt * 16 + kq * 4 + rg;
            const float r = 1.f / (1.f + __expf(-(ar[rg] + b_r)));
            const float z = 1.f / (1.f + __expf(-(az[rg] + b_z)));
            const float n = tanhf(ain[rg] + b_in + r * (ahn[rg] + b_hn));
            const float hnew = (1.f - z) * n + z * hp[rg];
            hp[rg] = hnew;
            out[((size_t)t * BB + be) * (2 * HH) + dir * HH + jg] = hnew;
            st16_coh(&hbw[(size_t)be * HH + jg], (u16)f2bf(hnew));
            if (s == TT - 1)
                out[(size_t)TT * BB * 2 * HH + (size_t)dir * BB * HH + (size_t)be * HH + jg] = hnew;
        }

        // ---- signal: syncthreads drains all waves' coherent stores (vmcnt(0)
        // before s_barrier), then one relaxed device-scope inc ----
        if (s < TT - 1) {
            __syncthreads();
            if (tid == 0)
                __hip_atomic_fetch_add(cnt, 1, __ATOMIC_RELAXED, __HIP_MEMORY_SCOPE_AGENT);
        }
    }
}

// ---- fallback: per-step launches, no ws ------------------------------------

__global__ __launch_bounds__(64) void gru_step_kernel_nows(
    const float* __restrict__ inp,
    const float* __restrict__ h0f, const float* __restrict__ h0b,
    const float* __restrict__ Wih_f, const float* __restrict__ Whh_f,
    const float* __restrict__ bih_f, const float* __restrict__ bhh_f,
    const float* __restrict__ Wih_b, const float* __restrict__ Whh_b,
    const float* __restrict__ bih_b, const float* __restrict__ bhh_b,
    float* __restrict__ out, int s)
{
    const int jt = blockIdx.x, mt = blockIdx.y, dir = blockIdx.z;
    const int lane = threadIdx.x;
    const int nm = lane & 15, kq = lane >> 4, j0 = jt * 16, koff = kq * 8;
    const int t  = dir ? (TT - 1 - s) : s;
    const int tp = dir ? (t + 1) : (t - 1);
    const float* Wih = dir ? Wih_b : Wih_f;
    const float* Whh = dir ? Whh_b : Whh_f;
    const float* bih = dir ? bih_b : bih_f;
    const float* bhh = dir ? bhh_b : bhh_f;
    const float* h0  = dir ? h0b : h0f;
    const int arow = mt * 16 + nm;
    const float* xrow = inp + ((size_t)t * BB + arow) * II;
    const float* hrow = (s == 0) ? (h0 + (size_t)arow * HH)
                                 : (out + ((size_t)tp * BB + arow) * 2 * HH + dir * HH);
    const float* wi0 = Wih + (size_t)(0 * HH + j0 + nm) * II;
    const float* wi1 = Wih + (size_t)(1 * HH + j0 + nm) * II;
    const float* wi2 = Wih + (size_t)(2 * HH + j0 + nm) * II;
    const float* wh0 = Whh + (size_t)(0 * HH + j0 + nm) * II;
    const float* wh1 = Whh + (size_t)(1 * HH + j0 + nm) * II;
    const float* wh2 = Whh + (size_t)(2 * HH + j0 + nm) * II;
    f32x4 ar = {0.f, 0.f, 0.f, 0.f};
    f32x4 az = ar, ain = ar, ahn = ar;
    #pragma unroll 4
    for (int k0 = 0; k0 < II; k0 += 32) {
        const int kk = k0 + koff;
        const short8 a = ldcvt(xrow + kk);
        ar  = __builtin_amdgcn_mfma_f32_16x16x32_bf16(a, ldcvt(wi0 + kk), ar, 0, 0, 0);
        az  = __builtin_amdgcn_mfma_f32_16x16x32_bf16(a, ldcvt(wi1 + kk), az, 0, 0, 0);
        ain = __builtin_amdgcn_mfma_f32_16x16x32_bf16(a, ldcvt(wi2 + kk), ain, 0, 0, 0);
    }
    #pragma unroll 4
    for (int k0 = 0; k0 < HH; k0 += 32) {
        const int kk = k0 + koff;
        const short8 a = ldcvt(hrow + kk);
        ar  = __builtin_amdgcn_mfma_f32_16x16x32_bf16(a, ldcvt(wh0 + kk), ar, 0, 0, 0);
        az  = __builtin_amdgcn_mfma_f32_16x16x32_bf16(a, ldcvt(wh1 + kk), az, 0, 0, 0);
        ahn = __builtin_amdgcn_mfma_f32_16x16x32_bf16(a, ldcvt(wh2 + kk), ahn, 0, 0, 0);
    }
    const int jg = j0 + nm;
    const float b_r  = bih[jg] + bhh[jg];
    const float b_z  = bih[HH + jg] + bhh[HH + jg];
    const float b_in = bih[2 * HH + jg];
    const float b_hn = bhh[2 * HH + jg];
    #pragma unroll
    for (int rg = 0; rg < 4; ++rg) {
        const int be = mt * 16 + kq * 4 + rg;
        const float hprev = (s == 0)
            ? h0[(size_t)be * HH + jg]
            : out[((size_t)tp * BB + be) * 2 * HH + dir * HH + jg];
        const float r = 1.f / (1.f + __expf(-(ar[rg] + b_r)));
        const float z = 1.f / (1.f + __expf(-(az[rg] + b_z)));
        const float n = tanhf(ain[rg] + b_in + r * (ahn[rg] + b_hn));
        const float hnew = (1.f - z) * n + z * hprev;
        out[((size_t)t * BB + be) * 2 * HH + dir * HH + jg] = hnew;
        if (s == TT - 1)
            out[(size_t)TT * BB * 2 * HH + (size_t)dir * BB * HH + (size_t)be * HH + jg] = hnew;
    }
}

// ---- launch ----------------------------------------------------------------

extern "C" void kernel_launch(void* const* d_in, const int* in_sizes, int n_in,
                              void* d_out, int out_size, void* d_ws, size_t ws_size,
                              hipStream_t stream) {
    (void)in_sizes; (void)n_in; (void)out_size;

    const float* inp   = (const float*)d_in[0];
    const float* h0f   = (const float*)d_in[1];
    const float* h0b   = (const float*)d_in[2];
    const float* Wih_f = (const float*)d_in[3];
    const float* Whh_f = (const float*)d_in[4];
    const float* bih_f = (const float*)d_in[5];
    const float* bhh_f = (const float*)d_in[6];
    const float* Wih_b = (const float*)d_in[7];
    const float* Whh_b = (const float*)d_in[8];
    const float* bih_b = (const float*)d_in[9];
    const float* bhh_b = (const float*)d_in[10];
    float* out = (float*)d_out;

    char* ws = (char*)d_ws;
    int*  bar  = (int*)(ws + WS_BAR_OFF);
    u16*  wsW  = (u16*)(ws + WS_W_OFF);
    u16*  xbf  = (u16*)(ws + WS_X_OFF);
    u16*  hbuf = (u16*)(ws + WS_HB_OFF);

    if (ws_size >= WS_NEED_A) {
        hipMemsetAsync(ws + WS_BAR_OFF, 0, 1024, stream);
        convert_w_kernel<<<1024, 256, 0, stream>>>(Wih_f, Whh_f, Wih_b, Whh_b, wsW);
        convert_x_kernel<<<2048, 256, 0, stream>>>(inp, xbf);
        convert_h0_kernel<<<64, 256, 0, stream>>>(h0f, h0b, hbuf);
        gru_persistent<<<32, 512, 0, stream>>>(
            h0f, h0b, bih_f, bhh_f, bih_b, bhh_b,
            wsW, xbf, hbuf, bar, out);
    } else {
        const dim3 grid(HH / 16, BB / 16, 2);
        for (int s = 0; s < TT; ++s) {
            gru_step_kernel_nows<<<grid, dim3(64), 0, stream>>>(
                inp, h0f, h0b, Wih_f, Whh_f, bih_f, bhh_f,
                Wih_b, Whh_b, bih_b, bhh_b, out, s);
        }
    }
}